// Round 7
// baseline (400.820 us; speedup 1.0000x reference)
//
#include <hip/hip_runtime.h>
#include <hip/hip_bf16.h>
#include <cmath>

#define N_NODES 50000
#define N_EDGES 800000
#define D_IN 256
#define D_HID 128
#define D_ENC 64
#define NBUK 128         // dest buckets, bucket = c >> 9 (98 used)
#define BSH 9
#define BMSK 511
#define BCAP 16384       // fixed bucket capacity (expected ~8.2K, huge margin)
#define PBF_EPT 8        // edges per thread in fused part path (4096/block @ 512 thr)
#define NPARTB 196       // ceil(N_EDGES/4096)
#define NGEMB 782        // ceil(N_NODES/64) GEMM tile-blocks
#define NCSRB 98         // ceil(N_NODES/512) CSR bucket-blocks
#define NG1ZB 3125       // N_NODES/16
#define NGZB  196        // ceil(N_NODES/256) gatherz blocks

typedef short short8 __attribute__((ext_vector_type(8)));
typedef float floatx4 __attribute__((ext_vector_type(4)));
typedef float floatx8 __attribute__((ext_vector_type(8)));
typedef unsigned short ushort8v __attribute__((ext_vector_type(8)));

static __device__ __forceinline__ unsigned short f2bf(float f) {
    unsigned int u = __float_as_uint(f);
    unsigned int r = (u + 0x7FFFu + ((u >> 16) & 1u)) >> 16;   // RNE
    return (unsigned short)r;
}
static __device__ __forceinline__ float bf2f(unsigned short u) {
    return __uint_as_float(((unsigned int)u) << 16);
}
static __device__ __forceinline__ floatx8 bf2f8(ushort8v u) {
    floatx8 f;
#pragma unroll
    for (int j = 0; j < 8; ++j) f[j] = bf2f(u[j]);
    return f;
}

// release: all block stores visible, then bump counter (device scope)
static __device__ __forceinline__ void block_release(int* ctr) {
    __syncthreads();
    if (threadIdx.x == 0) { __threadfence(); atomicAdd(ctr, 1); }
}
// acquire: spin until counter reaches n, then fence
static __device__ __forceinline__ void block_acquire(int* ctr, int n) {
    if (threadIdx.x == 0) {
        while (__hip_atomic_load(ctr, __ATOMIC_RELAXED, __HIP_MEMORY_SCOPE_AGENT) < n)
            __builtin_amdgcn_s_sleep(8);
        __threadfence();
    }
    __syncthreads();
}

// ---------------- W pre-swizzle into B-fragment layout (bf16) ----------------
static __device__ __forceinline__ void wswz(const float* __restrict__ W,
                                            unsigned short* __restrict__ Wsw,
                                            int t, int K, int N) {
    int KS = K / 32;
    int lane = t & 63;
    int ks   = (t >> 6) % KS;
    int ct   = (t >> 6) / KS;
    int m = lane & 15, quad = lane >> 4;
    int kbase = ks * 32 + quad * 8;
    int col   = ct * 16 + m;
#pragma unroll
    for (int j = 0; j < 8; ++j)
        Wsw[t * 8 + j] = f2bf(W[(size_t)(kbase + j) * N + col]);
}

// ---------------- k0: weight prep + bcur/ctr zero ----------------
__global__ __launch_bounds__(256) void prep_k(const float* __restrict__ W1,
                                              const float* __restrict__ W2,
                                              const float* __restrict__ b2,
                                              const float* __restrict__ Wfc,
                                              unsigned short* __restrict__ Wsw1,
                                              float* __restrict__ w2fc,
                                              float* __restrict__ b2fc,
                                              int* __restrict__ bcur,
                                              int* __restrict__ ctrs) {
    int t = blockIdx.x * 256 + threadIdx.x;
    if (t < 4096) wswz(W1, Wsw1, t, D_IN, D_HID);
    else if (t < 4224) {                      // w2fc[c] = sum_j W2[c][j] * Wfc[j]
        int c = t - 4096;
        float s = 0.0f;
#pragma unroll 8
        for (int j = 0; j < D_ENC; ++j) s += W2[c * D_ENC + j] * Wfc[j];
        w2fc[c] = s;
    } else if (t == 4224) {                   // b2fc = sum_j b2[j] * Wfc[j]
        float s = 0.0f;
        for (int j = 0; j < D_ENC; ++j) s += b2[j] * Wfc[j];
        b2fc[0] = s;
    } else if (t >= 4225 && t < 4225 + NBUK) {
        bcur[t - 4225] = 0;
    } else if (t == 4225 + NBUK || t == 4226 + NBUK) {
        ctrs[t - 4225 - NBUK] = 0;
    }
}

// ---------------- fused: radix part || layer-1 GEMM || (spin) bucket-CSR ----------------
// Blocks [0,196): partition 4096 edges -> bucket-grouped flush into brecs,
//   then release ctr0. rec = (src<<16)|dst; bucket b at [b*BCAP, +count).
// Blocks [196,978): MFMA GEMM tile H[r,:] = bf16(X[r,:] @ W1) (dinv deferred).
// Blocks [978,1076): acquire ctr0==196, then per-bucket CSR build — overlaps
//   the GEMM tail instead of serializing in a later dispatch.
// Dynamic LDS union: part 17920 / gemm 33792 / csr 36864 -> 36864 B.
__global__ __launch_bounds__(512) void fused_k(const int* __restrict__ rows,
                                               const int* __restrict__ cols,
                                               int* __restrict__ bcur,
                                               unsigned int* __restrict__ brecs,
                                               const float4* __restrict__ X4,
                                               const unsigned short* __restrict__ Wsw,
                                               unsigned short* __restrict__ H,
                                               int* __restrict__ rowptr,
                                               int* __restrict__ rowcnt,
                                               unsigned short* __restrict__ srcs,
                                               float* __restrict__ dinv,
                                               int* __restrict__ ctr0) {
    extern __shared__ char dynsm[];
    int tid = threadIdx.x;
    if (blockIdx.x < NPARTB) {
        // ---- partition path (512 threads, 4096 edges/block) ----
        unsigned int* recs = (unsigned int*)dynsm;        // 4096 u32 (16 KB)
        int* h     = (int*)(dynsm + 16384);               // NBUK
        int* ex    = h + NBUK;                            // NBUK
        int* gbase = ex + NBUK;                           // NBUK
        if (tid < NBUK) h[tid] = 0;
        __syncthreads();
        int e0 = blockIdx.x * 4096;
        unsigned int myrec[PBF_EPT];
        int myb[PBF_EPT];
#pragma unroll
        for (int j = 0; j < PBF_EPT; ++j) {
            int e = e0 + j * 512 + tid;
            if (e < N_EDGES) {
                int s = rows[e], d = cols[e];
                myrec[j] = ((unsigned int)s << 16) | (unsigned int)d;
                myb[j] = d >> BSH;
                atomicAdd(&h[myb[j]], 1);
            } else myb[j] = -1;
        }
        __syncthreads();
        if (tid < NBUK) {
            int c = h[tid];
            gbase[tid] = tid * BCAP + (c ? atomicAdd(&bcur[tid], c) : 0);
            ex[tid] = c;
        }
        __syncthreads();
        for (int off = 1; off < NBUK; off <<= 1) {
            int v = 0;
            if (tid < NBUK && tid >= off) v = ex[tid - off];
            __syncthreads();
            if (tid < NBUK) ex[tid] += v;
            __syncthreads();
        }
        if (tid < NBUK) { ex[tid] -= h[tid]; h[tid] = 0; }
        __syncthreads();
#pragma unroll
        for (int j = 0; j < PBF_EPT; ++j) {
            if (myb[j] >= 0) {
                int p = ex[myb[j]] + atomicAdd(&h[myb[j]], 1);
                recs[p] = myrec[j];
            }
        }
        __syncthreads();
        int w = tid >> 6, lane = tid & 63;
        for (int b = w; b < NBUK; b += 8) {
            int start = ex[b], cnt = h[b], gb = gbase[b];
            int lim = (b + 1) * BCAP;
            for (int i = lane; i < cnt; i += 64) {
                int gp = gb + i;
                if (gp < lim) brecs[gp] = recs[start + i];
            }
        }
        block_release(ctr0);
    } else if (blockIdx.x < NPARTB + NGEMB) {
        // ---- GEMM path (8 waves; 64-row tile; wave w: row-sub w&3, ct-half w>>2) ----
        constexpr int KP = D_IN + 8;   // 264
        unsigned short* As = (unsigned short*)dynsm;    // 64*KP u16
        int row0 = (blockIdx.x - NPARTB) * 64;
        for (int idx = tid; idx < 64 * 64; idx += 512) {
            int r = idx >> 6, c4 = idx & 63;
            int gr = row0 + r;
            float4 v = (gr < N_NODES) ? X4[(size_t)gr * 64 + c4] : float4{0, 0, 0, 0};
            __hip_bfloat162 p0 = __float22bfloat162_rn(float2{v.x, v.y});   // packed RNE cvt
            __hip_bfloat162 p1 = __float22bfloat162_rn(float2{v.z, v.w});
            uint2 u; u.x = *(unsigned int*)&p0; u.y = *(unsigned int*)&p1;
            *(uint2*)&As[r * KP + c4 * 4] = u;
        }
        __syncthreads();

        int w    = tid >> 6;
        int lane = tid & 63;
        int m    = lane & 15;
        int quad = lane >> 4;
        int rsub = w & 3;
        int cth  = w >> 2;              // 0/1: which 4 col-tiles

        floatx4 acc[4];
#pragma unroll
        for (int ct = 0; ct < 4; ++ct)
#pragma unroll
            for (int i = 0; i < 4; ++i) acc[ct][i] = 0.0f;

#pragma unroll
        for (int ks = 0; ks < D_IN / 32; ++ks) {
            short8 af = *(const short8*)&As[(rsub * 16 + m) * KP + ks * 32 + quad * 8];
#pragma unroll
            for (int ct = 0; ct < 4; ++ct) {
                int ct4 = cth * 4 + ct;
                short8 bf = *(const short8*)&Wsw[(size_t)((ct4 * (D_IN / 32) + ks) * 64 + lane) * 8];
                acc[ct] = __builtin_amdgcn_mfma_f32_16x16x32_bf16(af, bf, acc[ct], 0, 0, 0);
            }
        }

        int rbase = row0 + rsub * 16 + quad * 4;
#pragma unroll
        for (int ct = 0; ct < 4; ++ct) {
            int col = (cth * 4 + ct) * 16 + m;
#pragma unroll
            for (int reg = 0; reg < 4; ++reg) {
                int r = rbase + reg;
                if (r < N_NODES) H[(size_t)r * D_HID + col] = f2bf(acc[ct][reg]);
            }
        }
    } else {
        // ---- CSR path: wait for all part blocks, then build bucket ----
        block_acquire(ctr0, NPARTB);
        int* s   = (int*)dynsm;                       // 512 ints
        int* cur = (int*)(dynsm + 2048);              // 512 ints
        unsigned short* sl = (unsigned short*)(dynsm + 4096);   // BCAP u16 (32 KB)
        int b = blockIdx.x - NPARTB - NGEMB;
        int cb = bcur[b]; if (cb > BCAP) cb = BCAP;
        int ebeg = b * BCAP, eend = ebeg + cb;
        s[tid] = 0;
        __syncthreads();
        for (int e = ebeg + tid; e < eend; e += 512)
            atomicAdd(&s[brecs[e] & BMSK], 1);
        __syncthreads();
        int v = s[tid];
        for (int off = 1; off < 512; off <<= 1) {
            int t = (tid >= off) ? s[tid - off] : 0;
            __syncthreads();
            s[tid] += t;
            __syncthreads();
        }
        int excl = s[tid] - v;
        cur[tid] = excl;
        int node = (b << BSH) + tid;
        if (node < N_NODES) {
            rowptr[node] = ebeg + excl;
            rowcnt[node] = v;
            dinv[node] = rsqrtf((float)(v + 1));   // +1 self-loop
        }
        __syncthreads();
        for (int e = ebeg + tid; e < eend; e += 512) {
            unsigned int rec = brecs[e];
            int p = atomicAdd(&cur[rec & BMSK], 1);
            sl[p] = (unsigned short)(rec >> 16);          // LDS scatter
        }
        __syncthreads();
        int nw = (cb + 1) >> 1;
        unsigned int* s32 = (unsigned int*)(srcs + ebeg);
        const unsigned int* l32 = (const unsigned int*)sl;
        for (int t = tid; t < nw; t += 512) s32[t] = l32[t];
    }
}

// x8-deep WEIGHTED gather: acc += dinv[s] * h1raw[s]; 8 loads in flight.
#define WGATHER(SP)                                                            \
    {                                                                          \
        const auto* sp_ = (SP);                                                \
        int i = 0;                                                             \
        for (; i + 8 <= cnt; i += 8) {                                         \
            int s0 = sp_[i],     s1 = sp_[i + 1], s2 = sp_[i + 2], s3 = sp_[i + 3]; \
            int s4 = sp_[i + 4], s5 = sp_[i + 5], s6 = sp_[i + 6], s7 = sp_[i + 7]; \
            float w0 = dinv[s0], w1 = dinv[s1], w2 = dinv[s2], w3 = dinv[s3];  \
            float w4 = dinv[s4], w5 = dinv[s5], w6 = dinv[s6], w7 = dinv[s7];  \
            ushort8v v0 = hs[(size_t)s0 * 16 + d8], v1 = hs[(size_t)s1 * 16 + d8]; \
            ushort8v v2 = hs[(size_t)s2 * 16 + d8], v3 = hs[(size_t)s3 * 16 + d8]; \
            ushort8v v4 = hs[(size_t)s4 * 16 + d8], v5 = hs[(size_t)s5 * 16 + d8]; \
            ushort8v v6 = hs[(size_t)s6 * 16 + d8], v7 = hs[(size_t)s7 * 16 + d8]; \
            a0 += bf2f8(v0) * w0; a1 += bf2f8(v1) * w1;                        \
            a2 += bf2f8(v2) * w2; a3 += bf2f8(v3) * w3;                        \
            a0 += bf2f8(v4) * w4; a1 += bf2f8(v5) * w5;                        \
            a2 += bf2f8(v6) * w6; a3 += bf2f8(v7) * w7;                        \
        }                                                                      \
        if (i + 4 <= cnt) {                                                    \
            int s0 = sp_[i], s1 = sp_[i + 1], s2 = sp_[i + 2], s3 = sp_[i + 3]; \
            a0 += bf2f8(hs[(size_t)s0 * 16 + d8]) * dinv[s0];                  \
            a1 += bf2f8(hs[(size_t)s1 * 16 + d8]) * dinv[s1];                  \
            a2 += bf2f8(hs[(size_t)s2 * 16 + d8]) * dinv[s2];                  \
            a3 += bf2f8(hs[(size_t)s3 * 16 + d8]) * dinv[s3];                  \
            i += 4;                                                            \
        }                                                                      \
        for (; i < cnt; ++i) {                                                 \
            int s = sp_[i];                                                    \
            a0 += bf2f8(hs[(size_t)s * 16 + d8]) * dinv[s];                    \
        }                                                                      \
    }

// ---------------- fused g1z || (spin) scalar propagation + sigmoid ----------------
// Blocks [0,3125): z[v] = dinv[v]*( relu(dinv[v]*Σ dinv[s]*h1raw[s] + b1) @ w2fc ),
//   16 nodes/block, 16 lanes/node, CSR window in LDS; release ctr1.
// Blocks [3125,3321): acquire ctr1==3125; out[v] = sigmoid(dinv[v]*(Σ z[nbr]+z[v]) + b2fc + bfc).
__global__ __launch_bounds__(256) void g1zz_k(const ushort8v* __restrict__ hs,
                                              const int* __restrict__ rowptr,
                                              const int* __restrict__ rowcnt,
                                              const unsigned short* __restrict__ srcs,
                                              const float* __restrict__ dinv,
                                              const float4* __restrict__ b1_4,
                                              const float4* __restrict__ w2fc4,
                                              float* __restrict__ z,
                                              int* __restrict__ ctr1,
                                              const float* __restrict__ b2fc,
                                              const float* __restrict__ bfc,
                                              float* __restrict__ out) {
    __shared__ unsigned short sidx[1024];   // expected ~256 (Poisson), huge margin
    __shared__ int sb2[2];
    int tid = threadIdx.x;
    if (blockIdx.x < NG1ZB) {
        int nodeb = blockIdx.x * 16;    // 50000 = 3125*16 exactly
        int ln = tid >> 4;              // local node 0..15
        int d8 = tid & 15;
        int node = nodeb + ln;
        int beg = rowptr[node];
        int cnt = rowcnt[node];
        if (tid == 0)   sb2[0] = beg;         // ln==0
        if (tid == 240) sb2[1] = beg + cnt;   // ln==15
        ushort8v selfv = hs[(size_t)node * 16 + d8];   // hoisted self-loop row
        float di = dinv[node];
        __syncthreads();
        int base = sb2[0], total = sb2[1] - base;
        for (int t = tid; t < total && t < 1024; t += 256) sidx[t] = srcs[base + t];
        __syncthreads();

        floatx8 a0 = {0,0,0,0,0,0,0,0}, a1 = a0, a2 = a0, a3 = a0;
        if (total <= 1024) {
            WGATHER(sidx + (beg - base))
        } else {
            WGATHER(srcs + beg)
        }
        floatx8 acc = a0 + a1 + a2 + a3 + bf2f8(selfv) * di;
        float4 bA = b1_4[d8 * 2],  bB = b1_4[d8 * 2 + 1];
        float4 wA = w2fc4[d8 * 2], wB = w2fc4[d8 * 2 + 1];
        float s = fmaxf(di * acc[0] + bA.x, 0.0f) * wA.x
                + fmaxf(di * acc[1] + bA.y, 0.0f) * wA.y
                + fmaxf(di * acc[2] + bA.z, 0.0f) * wA.z
                + fmaxf(di * acc[3] + bA.w, 0.0f) * wA.w
                + fmaxf(di * acc[4] + bB.x, 0.0f) * wB.x
                + fmaxf(di * acc[5] + bB.y, 0.0f) * wB.y
                + fmaxf(di * acc[6] + bB.z, 0.0f) * wB.z
                + fmaxf(di * acc[7] + bB.w, 0.0f) * wB.w;
#pragma unroll
        for (int off = 8; off; off >>= 1) s += __shfl_xor(s, off, 16);
        if (d8 == 0) z[node] = di * s;
        block_release(ctr1);
    } else {
        block_acquire(ctr1, NG1ZB);
        int v = (blockIdx.x - NG1ZB) * 256 + tid;
        if (v >= N_NODES) return;
        int beg = rowptr[v], cnt = rowcnt[v];
        float s0 = z[v], s1 = 0.0f, s2 = 0.0f, s3 = 0.0f;
        int i = beg, end = beg + cnt;
        for (; i + 4 <= end; i += 4) {
            s0 += z[srcs[i]];
            s1 += z[srcs[i + 1]];
            s2 += z[srcs[i + 2]];
            s3 += z[srcs[i + 3]];
        }
        for (; i < end; ++i) s0 += z[srcs[i]];
        float p = dinv[v] * (s0 + s1 + s2 + s3) + b2fc[0] + bfc[0];
        out[v] = 1.0f / (1.0f + expf(-p));
    }
}

extern "C" void kernel_launch(void* const* d_in, const int* in_sizes, int n_in,
                              void* d_out, int out_size, void* d_ws, size_t ws_size,
                              hipStream_t stream) {
    const float* x   = (const float*)d_in[0];
    const int*   ei  = (const int*)d_in[1];     // [2, E] int32
    const float* W1  = (const float*)d_in[2];
    const float* b1  = (const float*)d_in[3];
    const float* W2  = (const float*)d_in[4];
    const float* b2  = (const float*)d_in[5];
    const float* Wfc = (const float*)d_in[6];
    const float* bfc = (const float*)d_in[7];
    float* out = (float*)d_out;

    const int* rows = ei;             // sources
    const int* cols = ei + N_EDGES;   // targets

    // workspace layout (16B alignment kept for vector types)
    float* ws     = (float*)d_ws;
    float* dinv   = ws;                                   // 50048 f
    int*   rowptr = (int*)(ws + 50048);                   // 50048
    int*   rowcnt = rowptr + 50048;                       // 50048
    int*   bcur   = rowcnt + 50048;                       // 128
    unsigned int* brecs = (unsigned int*)(bcur + 128);    // NBUK*BCAP u32 (8MB)
    unsigned short* srcs = (unsigned short*)(brecs + NBUK * BCAP);  // NBUK*BCAP u16 (4MB)
    unsigned short* h1 = srcs + (size_t)NBUK * BCAP;               // 6.4M us (12.8MB)
    unsigned short* Wsw1 = h1 + (size_t)N_NODES * D_HID;           // 32768 us
    float* z    = (float*)(Wsw1 + (size_t)D_IN * D_HID);           // 50000 f
    float* w2fc = z + 50000;                                       // 128 f
    float* b2fc = w2fc + 128;                                      // 1 f
    int*   ctrs = (int*)(b2fc + 1);                                // 2 ints (ctr0, ctr1)

    // ---- k0: weight swizzle + FC fold + bcur/ctr zero ----
    prep_k<<<18, 256, 0, stream>>>(W1, W2, b2, Wfc, Wsw1, w2fc, b2fc, bcur, ctrs);

    // ---- fused: part (196) || GEMM (782) || spin-CSR (98) ----
    fused_k<<<NPARTB + NGEMB + NCSRB, 512, 36864, stream>>>(
        rows, cols, bcur, brecs, (const float4*)x, Wsw1, h1,
        rowptr, rowcnt, srcs, dinv, ctrs);

    // ---- fused: g1z (3125) || spin-gatherz (196) ----
    g1zz_k<<<NG1ZB + NGZB, 256, 0, stream>>>((const ushort8v*)h1, rowptr, rowcnt, srcs, dinv,
                                             (const float4*)b1, (const float4*)w2fc, z,
                                             ctrs + 1, b2fc, bfc, out);
}

// Round 8
// 162.740 us; speedup vs baseline: 2.4629x; 2.4629x over previous
//
#include <hip/hip_runtime.h>
#include <hip/hip_bf16.h>
#include <cmath>

#define N_NODES 50000
#define N_EDGES 800000
#define D_IN 256
#define D_HID 128
#define D_ENC 64
#define NBUK 128         // dest buckets, bucket = c >> 9 (98 used)
#define BSH 9
#define BMSK 511
#define BCAP 16384       // fixed bucket capacity (expected ~8.2K, huge margin)
#define PBF_EPT 8        // edges per thread in part path (4096/block @ 512 thr)
#define NPARTB 196       // ceil(N_EDGES/4096)
#define NGEMB 782        // ceil(50048/64) GEMM tile-blocks total
#define NGEMB_H 391      // half
#define GEMM_H2_ROW0 (NGEMB_H * 64)   // 25024
#define NCSRB 98         // ceil(N_NODES/512) CSR bucket-blocks

typedef short short8 __attribute__((ext_vector_type(8)));
typedef float floatx4 __attribute__((ext_vector_type(4)));
typedef float floatx8 __attribute__((ext_vector_type(8)));
typedef unsigned short ushort8v __attribute__((ext_vector_type(8)));

static __device__ __forceinline__ unsigned short f2bf(float f) {
    unsigned int u = __float_as_uint(f);
    unsigned int r = (u + 0x7FFFu + ((u >> 16) & 1u)) >> 16;   // RNE
    return (unsigned short)r;
}
static __device__ __forceinline__ float bf2f(unsigned short u) {
    return __uint_as_float(((unsigned int)u) << 16);
}
static __device__ __forceinline__ floatx8 bf2f8(ushort8v u) {
    floatx8 f;
#pragma unroll
    for (int j = 0; j < 8; ++j) f[j] = bf2f(u[j]);
    return f;
}

// ---------------- W pre-swizzle into B-fragment layout (bf16) ----------------
static __device__ __forceinline__ void wswz(const float* __restrict__ W,
                                            unsigned short* __restrict__ Wsw,
                                            int t, int K, int N) {
    int KS = K / 32;
    int lane = t & 63;
    int ks   = (t >> 6) % KS;
    int ct   = (t >> 6) / KS;
    int m = lane & 15, quad = lane >> 4;
    int kbase = ks * 32 + quad * 8;
    int col   = ct * 16 + m;
#pragma unroll
    for (int j = 0; j < 8; ++j)
        Wsw[t * 8 + j] = f2bf(W[(size_t)(kbase + j) * N + col]);
}

// ---------------- k0: weight prep + bcur zero ----------------
__global__ __launch_bounds__(256) void prep_k(const float* __restrict__ W1,
                                              const float* __restrict__ W2,
                                              const float* __restrict__ b2,
                                              const float* __restrict__ Wfc,
                                              unsigned short* __restrict__ Wsw1,
                                              float* __restrict__ w2fc,
                                              float* __restrict__ b2fc,
                                              int* __restrict__ bcur) {
    int t = blockIdx.x * 256 + threadIdx.x;
    if (t < 4096) wswz(W1, Wsw1, t, D_IN, D_HID);
    else if (t < 4224) {                      // w2fc[c] = sum_j W2[c][j] * Wfc[j]
        int c = t - 4096;
        float s = 0.0f;
#pragma unroll 8
        for (int j = 0; j < D_ENC; ++j) s += W2[c * D_ENC + j] * Wfc[j];
        w2fc[c] = s;
    } else if (t == 4224) {                   // b2fc = sum_j b2[j] * Wfc[j]
        float s = 0.0f;
        for (int j = 0; j < D_ENC; ++j) s += b2[j] * Wfc[j];
        b2fc[0] = s;
    } else if (t >= 4225 && t < 4225 + NBUK) {
        bcur[t - 4225] = 0;
    }
}

// ---------------- device: radix partition of one 4096-edge chunk ----------------
static __device__ void part_path(char* dynsm, int bid,
                                 const int* __restrict__ rows,
                                 const int* __restrict__ cols,
                                 int* __restrict__ bcur,
                                 unsigned int* __restrict__ brecs) {
    unsigned int* recs = (unsigned int*)dynsm;        // 4096 u32 (16 KB)
    int* h     = (int*)(dynsm + 16384);               // NBUK
    int* ex    = h + NBUK;                            // NBUK
    int* gbase = ex + NBUK;                           // NBUK
    int tid = threadIdx.x;
    if (tid < NBUK) h[tid] = 0;
    __syncthreads();
    int e0 = bid * 4096;
    unsigned int myrec[PBF_EPT];
    int myb[PBF_EPT];
#pragma unroll
    for (int j = 0; j < PBF_EPT; ++j) {
        int e = e0 + j * 512 + tid;
        if (e < N_EDGES) {
            int s = __builtin_nontemporal_load(&rows[e]);   // single-touch stream
            int d = __builtin_nontemporal_load(&cols[e]);
            myrec[j] = ((unsigned int)s << 16) | (unsigned int)d;
            myb[j] = d >> BSH;
            atomicAdd(&h[myb[j]], 1);
        } else myb[j] = -1;
    }
    __syncthreads();
    if (tid < NBUK) {
        int c = h[tid];
        gbase[tid] = tid * BCAP + (c ? atomicAdd(&bcur[tid], c) : 0);
        ex[tid] = c;
    }
    __syncthreads();
    for (int off = 1; off < NBUK; off <<= 1) {
        int v = 0;
        if (tid < NBUK && tid >= off) v = ex[tid - off];
        __syncthreads();
        if (tid < NBUK) ex[tid] += v;
        __syncthreads();
    }
    if (tid < NBUK) { ex[tid] -= h[tid]; h[tid] = 0; }
    __syncthreads();
#pragma unroll
    for (int j = 0; j < PBF_EPT; ++j) {
        if (myb[j] >= 0) {
            int p = ex[myb[j]] + atomicAdd(&h[myb[j]], 1);
            recs[p] = myrec[j];
        }
    }
    __syncthreads();
    int w = tid >> 6, lane = tid & 63;
    for (int b = w; b < NBUK; b += 8) {
        int start = ex[b], cnt = h[b], gb = gbase[b];
        int lim = (b + 1) * BCAP;
        for (int i = lane; i < cnt; i += 64) {
            int gp = gb + i;
            if (gp < lim) brecs[gp] = recs[start + i];
        }
    }
}

// ---------------- device: per-bucket CSR build (LDS-staged scatter) ----------------
static __device__ void csr_path(char* dynsm, int b,
                                const unsigned int* __restrict__ brecs,
                                const int* __restrict__ bcur,
                                int* __restrict__ rowptr,
                                int* __restrict__ rowcnt,
                                unsigned short* __restrict__ srcs,
                                float* __restrict__ dinv) {
    int* s   = (int*)dynsm;                       // 512 ints
    int* cur = (int*)(dynsm + 2048);              // 512 ints
    unsigned short* sl = (unsigned short*)(dynsm + 4096);   // BCAP u16 (32 KB)
    int tid = threadIdx.x;
    int cb = bcur[b]; if (cb > BCAP) cb = BCAP;
    int ebeg = b * BCAP, eend = ebeg + cb;
    s[tid] = 0;
    __syncthreads();
    for (int e = ebeg + tid; e < eend; e += 512)
        atomicAdd(&s[brecs[e] & BMSK], 1);
    __syncthreads();
    int v = s[tid];
    for (int off = 1; off < 512; off <<= 1) {
        int t = (tid >= off) ? s[tid - off] : 0;
        __syncthreads();
        s[tid] += t;
        __syncthreads();
    }
    int excl = s[tid] - v;
    cur[tid] = excl;
    int node = (b << BSH) + tid;
    if (node < N_NODES) {
        rowptr[node] = ebeg + excl;
        rowcnt[node] = v;
        dinv[node] = rsqrtf((float)(v + 1));   // +1 self-loop
    }
    __syncthreads();
    for (int e = ebeg + tid; e < eend; e += 512) {
        unsigned int rec = brecs[e];
        int p = atomicAdd(&cur[rec & BMSK], 1);
        sl[p] = (unsigned short)(rec >> 16);          // LDS scatter
    }
    __syncthreads();
    int nw = (cb + 1) >> 1;                           // coalesced u32 flush
    unsigned int* s32 = (unsigned int*)(srcs + ebeg);
    const unsigned int* l32 = (const unsigned int*)sl;
    for (int t = tid; t < nw; t += 512) s32[t] = l32[t];
}

// ---------------- device: one 64-row MFMA GEMM tile ----------------
static __device__ void gemm_path(char* dynsm, int row0,
                                 const floatx4* __restrict__ X4,
                                 const unsigned short* __restrict__ Wsw,
                                 unsigned short* __restrict__ H) {
    constexpr int KP = D_IN + 8;   // 264
    unsigned short* As = (unsigned short*)dynsm;    // 64*KP u16
    int tid = threadIdx.x;
    for (int idx = tid; idx < 64 * 64; idx += 512) {
        int r = idx >> 6, c4 = idx & 63;
        int gr = row0 + r;
        floatx4 v = (gr < N_NODES) ? __builtin_nontemporal_load(&X4[(size_t)gr * 64 + c4])
                                   : (floatx4){0, 0, 0, 0};   // X is single-touch
        __hip_bfloat162 p0 = __float22bfloat162_rn(float2{v[0], v[1]});   // packed RNE cvt
        __hip_bfloat162 p1 = __float22bfloat162_rn(float2{v[2], v[3]});
        uint2 u; u.x = *(unsigned int*)&p0; u.y = *(unsigned int*)&p1;
        *(uint2*)&As[r * KP + c4 * 4] = u;
    }
    __syncthreads();

    int w    = tid >> 6;
    int lane = tid & 63;
    int m    = lane & 15;
    int quad = lane >> 4;
    int rsub = w & 3;
    int cth  = w >> 2;              // 0/1: which 4 col-tiles

    floatx4 acc[4];
#pragma unroll
    for (int ct = 0; ct < 4; ++ct)
#pragma unroll
        for (int i = 0; i < 4; ++i) acc[ct][i] = 0.0f;

#pragma unroll
    for (int ks = 0; ks < D_IN / 32; ++ks) {
        short8 af = *(const short8*)&As[(rsub * 16 + m) * KP + ks * 32 + quad * 8];
#pragma unroll
        for (int ct = 0; ct < 4; ++ct) {
            int ct4 = cth * 4 + ct;
            short8 bf = *(const short8*)&Wsw[(size_t)((ct4 * (D_IN / 32) + ks) * 64 + lane) * 8];
            acc[ct] = __builtin_amdgcn_mfma_f32_16x16x32_bf16(af, bf, acc[ct], 0, 0, 0);
        }
    }

    int rbase = row0 + rsub * 16 + quad * 4;
#pragma unroll
    for (int ct = 0; ct < 4; ++ct) {
        int col = (cth * 4 + ct) * 16 + m;
#pragma unroll
        for (int reg = 0; reg < 4; ++reg) {
            int r = rbase + reg;
            if (r < N_NODES) H[(size_t)r * D_HID + col] = f2bf(acc[ct][reg]);
        }
    }
}

// ---------------- D1: part (196) || GEMM half-A (391) ----------------
__global__ __launch_bounds__(512) void pg1_k(const int* __restrict__ rows,
                                             const int* __restrict__ cols,
                                             int* __restrict__ bcur,
                                             unsigned int* __restrict__ brecs,
                                             const floatx4* __restrict__ X4,
                                             const unsigned short* __restrict__ Wsw,
                                             unsigned short* __restrict__ H) {
    extern __shared__ char dynsm[];
    if (blockIdx.x < NPARTB)
        part_path(dynsm, blockIdx.x, rows, cols, bcur, brecs);
    else
        gemm_path(dynsm, (blockIdx.x - NPARTB) * 64, X4, Wsw, H);
}

// ---------------- D2: csr (98) || GEMM half-B (391) — csr hides under gemm ----------------
__global__ __launch_bounds__(512) void cg2_k(const unsigned int* __restrict__ brecs,
                                             const int* __restrict__ bcur,
                                             int* __restrict__ rowptr,
                                             int* __restrict__ rowcnt,
                                             unsigned short* __restrict__ srcs,
                                             float* __restrict__ dinv,
                                             const floatx4* __restrict__ X4,
                                             const unsigned short* __restrict__ Wsw,
                                             unsigned short* __restrict__ H) {
    extern __shared__ char dynsm[];
    if (blockIdx.x < NCSRB)
        csr_path(dynsm, blockIdx.x, brecs, bcur, rowptr, rowcnt, srcs, dinv);
    else
        gemm_path(dynsm, (blockIdx.x - NCSRB) * 64 + GEMM_H2_ROW0, X4, Wsw, H);
}

// x8-deep WEIGHTED gather: acc += dinv[s] * h1raw[s]; 8 loads in flight.
#define WGATHER(SP)                                                            \
    {                                                                          \
        const auto* sp_ = (SP);                                                \
        int i = 0;                                                             \
        for (; i + 8 <= cnt; i += 8) {                                         \
            int s0 = sp_[i],     s1 = sp_[i + 1], s2 = sp_[i + 2], s3 = sp_[i + 3]; \
            int s4 = sp_[i + 4], s5 = sp_[i + 5], s6 = sp_[i + 6], s7 = sp_[i + 7]; \
            float w0 = dinv[s0], w1 = dinv[s1], w2 = dinv[s2], w3 = dinv[s3];  \
            float w4 = dinv[s4], w5 = dinv[s5], w6 = dinv[s6], w7 = dinv[s7];  \
            ushort8v v0 = hs[(size_t)s0 * 16 + d8], v1 = hs[(size_t)s1 * 16 + d8]; \
            ushort8v v2 = hs[(size_t)s2 * 16 + d8], v3 = hs[(size_t)s3 * 16 + d8]; \
            ushort8v v4 = hs[(size_t)s4 * 16 + d8], v5 = hs[(size_t)s5 * 16 + d8]; \
            ushort8v v6 = hs[(size_t)s6 * 16 + d8], v7 = hs[(size_t)s7 * 16 + d8]; \
            a0 += bf2f8(v0) * w0; a1 += bf2f8(v1) * w1;                        \
            a2 += bf2f8(v2) * w2; a3 += bf2f8(v3) * w3;                        \
            a0 += bf2f8(v4) * w4; a1 += bf2f8(v5) * w5;                        \
            a2 += bf2f8(v6) * w6; a3 += bf2f8(v7) * w7;                        \
        }                                                                      \
        if (i + 4 <= cnt) {                                                    \
            int s0 = sp_[i], s1 = sp_[i + 1], s2 = sp_[i + 2], s3 = sp_[i + 3]; \
            a0 += bf2f8(hs[(size_t)s0 * 16 + d8]) * dinv[s0];                  \
            a1 += bf2f8(hs[(size_t)s1 * 16 + d8]) * dinv[s1];                  \
            a2 += bf2f8(hs[(size_t)s2 * 16 + d8]) * dinv[s2];                  \
            a3 += bf2f8(hs[(size_t)s3 * 16 + d8]) * dinv[s3];                  \
            i += 4;                                                            \
        }                                                                      \
        for (; i < cnt; ++i) {                                                 \
            int s = sp_[i];                                                    \
            a0 += bf2f8(hs[(size_t)s * 16 + d8]) * dinv[s];                    \
        }                                                                      \
    }

// ---------------- fused gather1 + relu + FC-folded projection ----------------
// z[v] = dinv[v] * ( relu(dinv[v]*Σ dinv[s]*h1raw[s] + b1) @ w2fc )  — scalar per node.
// Block = 256 (4 waves), 16 nodes/block, 16 lanes/node; CSR window in LDS.
__global__ __launch_bounds__(256) void g1z_k(const ushort8v* __restrict__ hs,
                                             const int* __restrict__ rowptr,
                                             const int* __restrict__ rowcnt,
                                             const unsigned short* __restrict__ srcs,
                                             const float* __restrict__ dinv,
                                             const float4* __restrict__ b1_4,
                                             const float4* __restrict__ w2fc4,
                                             float* __restrict__ z) {
    __shared__ unsigned short sidx[1024];   // expected ~256 (Poisson), huge margin
    __shared__ int sb2[2];
    int tid = threadIdx.x;
    int nodeb = blockIdx.x * 16;    // 50000 = 3125*16 exactly
    int ln = tid >> 4;              // local node 0..15
    int d8 = tid & 15;
    int node = nodeb + ln;
    int beg = rowptr[node];
    int cnt = rowcnt[node];
    if (tid == 0)   sb2[0] = beg;         // ln==0
    if (tid == 240) sb2[1] = beg + cnt;   // ln==15
    ushort8v selfv = hs[(size_t)node * 16 + d8];   // hoisted self-loop row
    float di = dinv[node];
    __syncthreads();
    int base = sb2[0], total = sb2[1] - base;
    for (int t = tid; t < total && t < 1024; t += 256) sidx[t] = srcs[base + t];
    __syncthreads();

    floatx8 a0 = {0,0,0,0,0,0,0,0}, a1 = a0, a2 = a0, a3 = a0;
    if (total <= 1024) {
        WGATHER(sidx + (beg - base))
    } else {
        WGATHER(srcs + beg)
    }
    floatx8 acc = a0 + a1 + a2 + a3 + bf2f8(selfv) * di;
    float4 bA = b1_4[d8 * 2],  bB = b1_4[d8 * 2 + 1];
    float4 wA = w2fc4[d8 * 2], wB = w2fc4[d8 * 2 + 1];
    float s = fmaxf(di * acc[0] + bA.x, 0.0f) * wA.x
            + fmaxf(di * acc[1] + bA.y, 0.0f) * wA.y
            + fmaxf(di * acc[2] + bA.z, 0.0f) * wA.z
            + fmaxf(di * acc[3] + bA.w, 0.0f) * wA.w
            + fmaxf(di * acc[4] + bB.x, 0.0f) * wB.x
            + fmaxf(di * acc[5] + bB.y, 0.0f) * wB.y
            + fmaxf(di * acc[6] + bB.z, 0.0f) * wB.z
            + fmaxf(di * acc[7] + bB.w, 0.0f) * wB.w;
#pragma unroll
    for (int off = 8; off; off >>= 1) s += __shfl_xor(s, off, 16);
    if (d8 == 0) z[node] = di * s;
}

// ---------------- scalar propagation + sigmoid ----------------
__global__ __launch_bounds__(256) void gatherz_k(const float* __restrict__ z,
                                                 const int* __restrict__ rowptr,
                                                 const int* __restrict__ rowcnt,
                                                 const unsigned short* __restrict__ srcs,
                                                 const float* __restrict__ dinv,
                                                 const float* __restrict__ b2fc,
                                                 const float* __restrict__ bfc,
                                                 float* __restrict__ out) {
    int v = blockIdx.x * 256 + threadIdx.x;
    if (v >= N_NODES) return;
    int beg = rowptr[v], cnt = rowcnt[v];
    float s0 = z[v], s1 = 0.0f, s2 = 0.0f, s3 = 0.0f;
    int i = beg, end = beg + cnt;
    for (; i + 4 <= end; i += 4) {
        s0 += z[srcs[i]];
        s1 += z[srcs[i + 1]];
        s2 += z[srcs[i + 2]];
        s3 += z[srcs[i + 3]];
    }
    for (; i < end; ++i) s0 += z[srcs[i]];
    float p = dinv[v] * (s0 + s1 + s2 + s3) + b2fc[0] + bfc[0];
    out[v] = 1.0f / (1.0f + expf(-p));
}

extern "C" void kernel_launch(void* const* d_in, const int* in_sizes, int n_in,
                              void* d_out, int out_size, void* d_ws, size_t ws_size,
                              hipStream_t stream) {
    const float* x   = (const float*)d_in[0];
    const int*   ei  = (const int*)d_in[1];     // [2, E] int32
    const float* W1  = (const float*)d_in[2];
    const float* b1  = (const float*)d_in[3];
    const float* W2  = (const float*)d_in[4];
    const float* b2  = (const float*)d_in[5];
    const float* Wfc = (const float*)d_in[6];
    const float* bfc = (const float*)d_in[7];
    float* out = (float*)d_out;

    const int* rows = ei;             // sources
    const int* cols = ei + N_EDGES;   // targets

    // workspace layout (16B alignment kept for vector types)
    float* ws     = (float*)d_ws;
    float* dinv   = ws;                                   // 50048 f
    int*   rowptr = (int*)(ws + 50048);                   // 50048
    int*   rowcnt = rowptr + 50048;                       // 50048
    int*   bcur   = rowcnt + 50048;                       // 128
    unsigned int* brecs = (unsigned int*)(bcur + 128);    // NBUK*BCAP u32 (8MB)
    unsigned short* srcs = (unsigned short*)(brecs + NBUK * BCAP);  // NBUK*BCAP u16 (4MB)
    unsigned short* h1 = srcs + (size_t)NBUK * BCAP;               // 6.4M us (12.8MB)
    unsigned short* Wsw1 = h1 + (size_t)N_NODES * D_HID;           // 32768 us
    float* z    = (float*)(Wsw1 + (size_t)D_IN * D_HID);           // 50000 f
    float* w2fc = z + 50000;                                       // 128 f
    float* b2fc = w2fc + 128;                                      // 1 f

    // ---- k0: weight swizzle + FC fold + bcur zero ----
    prep_k<<<18, 256, 0, stream>>>(W1, W2, b2, Wfc, Wsw1, w2fc, b2fc, bcur);

    // ---- D1: radix partition (196) || GEMM rows [0, 25024) (391) ----
    pg1_k<<<NPARTB + NGEMB_H, 512, 36864, stream>>>(rows, cols, bcur, brecs,
                                                    (const floatx4*)x, Wsw1, h1);

    // ---- D2: bucket-CSR (98) || GEMM rows [25024, 50048) (391) ----
    cg2_k<<<NCSRB + NGEMB_H, 512, 36864, stream>>>(brecs, bcur, rowptr, rowcnt, srcs, dinv,
                                                   (const floatx4*)x, Wsw1, h1);

    // ---- fused gather1 (dinv-weighted) + relu + (W2 @ Wfc) projection -> scalar z ----
    g1z_k<<<N_NODES / 16, 256, 0, stream>>>((const ushort8v*)h1, rowptr, rowcnt, srcs, dinv,
                                            (const float4*)b1, (const float4*)w2fc, z);

    // ---- scalar propagation + sigmoid ----
    gatherz_k<<<(N_NODES + 255) / 256, 256, 0, stream>>>(z, rowptr, rowcnt, srcs, dinv,
                                                         b2fc, bfc, out);
}